// Round 7
// baseline (274.948 us; speedup 1.0000x reference)
//
#include <hip/hip_runtime.h>
#include <hip/hip_bf16.h>
#include <string.h>

#define B_ 8
#define N_ 50000
#define F_ 32
#define S_ 16
#define O_ 64
#define K_ (F_ * S_)            // 512
#define XELEMS (B_ * N_ * F_)   // 12.8M
#define TPB (N_ / 16)           // 3125 tiles per batch
#define BPB 196                 // tile-groups per batch (196*16 = 3136 >= 3125)
#define GRID_PERS 512           // 2 blocks/CU, all co-resident -> no generation tail

typedef __attribute__((ext_vector_type(8))) short bf16x8;
typedef __attribute__((ext_vector_type(4))) float f32x4;
typedef __attribute__((ext_vector_type(4))) int int4v;

union bfpack { bf16x8 v; __hip_bfloat16 h[8]; };

// ---- Prepass: W -> bf16 fragment-swizzled (64 KB) + x -> bf16 rows (25.6 MB) ----
// Also resets the 8 per-batch work counters (stream-ordered before spiral;
// runs every graph replay, so counters never need a host-side memset).
__global__ __launch_bounds__(256) void prep_kernel(const float* __restrict__ W,
                                                   unsigned short* __restrict__ Wb,
                                                   const float* __restrict__ x,
                                                   unsigned short* __restrict__ xb,
                                                   unsigned int* __restrict__ ctr) {
    int bid = blockIdx.x;
    if (bid == 0 && threadIdx.x < 8) ctr[threadIdx.x] = 0u;
    if (bid < 128) {
        int i = bid * 256 + threadIdx.x; // [0, 32768)
        int j = i & 7;
        int o = (i >> 3) & 63;
        int qk = i >> 9;
        int quad = qk & 3;
        int kt = qk >> 2;
        __hip_bfloat16 h = __float2bfloat16(W[o * K_ + kt * 32 + quad * 8 + j]);
        unsigned short u; memcpy(&u, &h, 2);
        Wb[i] = u;
    } else {
        int i = (bid - 128) * 256 + threadIdx.x; // [0, 1.6M) groups of 8
        if (i < XELEMS / 8) {
            size_t base = (size_t)i * 8;
            f32x4 a = __builtin_nontemporal_load((const f32x4*)(x + base));
            f32x4 b = __builtin_nontemporal_load((const f32x4*)(x + base + 4));
            bfpack p;
            p.h[0] = __float2bfloat16(a[0]); p.h[1] = __float2bfloat16(a[1]);
            p.h[2] = __float2bfloat16(a[2]); p.h[3] = __float2bfloat16(a[3]);
            p.h[4] = __float2bfloat16(b[0]); p.h[5] = __float2bfloat16(b[1]);
            p.h[6] = __float2bfloat16(b[2]); p.h[7] = __float2bfloat16(b[3]);
            *(bf16x8*)(xb + base) = p.v;
        }
    }
}

// ================= r4's 94 us spiral body, verbatim =================
// LDS-DMA deep pipeline: gathers via global_load_lds into a per-wave 4-slot
// ring (no dest VGPRs -> depth is structural), pinned issue order, counted
// vmcnt (24 steady / 16 / 8 / 0 tail), W fragments from L1/L2 (r6 showed the
// W stream is not the bottleneck), cached epilogue stores (exact WRITE_SIZE).
__device__ __forceinline__ void spiral_body(
        const unsigned short* __restrict__ xb, const int* __restrict__ adj,
        const unsigned short* __restrict__ Wb, const float* __restrict__ bias,
        float* __restrict__ out, unsigned char* ringw,
        int b, int tib0, int lane, int m16, int quad)
{
    int rowbase[4], nn[4];
#pragma unroll
    for (int vt = 0; vt < 4; ++vt) {
        int t = tib0 + vt;
        if (t >= TPB) t = TPB - 1; // clamp: duplicate identical stores, benign
        nn[vt] = t * 16;
        rowbase[vt] = b * N_ + t * 16;
    }
    const size_t xbase = (size_t)b * N_ * F_;

    // All adj up front (nt: read-once stream). 16 x int4.
    int4v aj_all[4][4]; // [vt][kt4]
#pragma unroll
    for (int vt = 0; vt < 4; ++vt)
#pragma unroll
        for (int kt4 = 0; kt4 < 4; ++kt4)
            aj_all[vt][kt4] = __builtin_nontemporal_load(
                (const int4v*)(adj + (size_t)(rowbase[vt] + m16) * S_ + kt4 * 4));

    f32x4 acc[4][4];
#pragma unroll
    for (int vt = 0; vt < 4; ++vt)
#pragma unroll
        for (int nt = 0; nt < 4; ++nt)
            acc[vt][nt] = (f32x4){0.f, 0.f, 0.f, 0.f};

    bf16x8 wfp[4][4]; // W fragment pipeline: [ring slot][nt], static indices only

#define GATHER_ISSUE(g_)                                                                   \
    do {                                                                                   \
        if ((g_) < 16) {                                                                   \
            const int kt4_ = (g_) >> 2, q_ = (g_) & 3;                                     \
            _Pragma("unroll")                                                              \
            for (int vt = 0; vt < 4; ++vt) {                                               \
                int a_ = aj_all[vt][kt4_][q_];                                             \
                const unsigned short* src_ = xb + xbase + (size_t)a_ * F_ + quad * 8;      \
                __builtin_amdgcn_global_load_lds(                                          \
                    (const __attribute__((address_space(1))) void*)src_,                   \
                    (__attribute__((address_space(3))) void*)(ringw + ((((g_) & 3) * 4 + vt) << 10)), \
                    16, 0, 0);                                                             \
            }                                                                              \
        }                                                                                  \
    } while (0)

#define LOAD_W(g_)                                                                         \
    do {                                                                                   \
        if ((g_) < 16) {                                                                   \
            _Pragma("unroll")                                                              \
            for (int nt = 0; nt < 4; ++nt)                                                 \
                wfp[(g_) & 3][nt] = *(const bf16x8*)(                                      \
                    Wb + (size_t)(((g_) * 4 + quad) * 64 + nt * 16 + m16) * 8);            \
        }                                                                                  \
    } while (0)

#define SB __builtin_amdgcn_sched_barrier(0)

    // Prologue FIFO: C0 W0 C1 W1 C2 W2 (24 vmem in flight; the 16 earlier adj
    // loads drain first under the same counted waits — in-order retirement).
    GATHER_ISSUE(0); SB; LOAD_W(0); SB;
    GATHER_ISSUE(1); SB; LOAD_W(1); SB;
    GATHER_ISSUE(2); SB; LOAD_W(2); SB;

#pragma unroll
    for (int g = 0; g < 16; ++g) {
        GATHER_ISSUE(g + 3); SB;
        LOAD_W(g + 3); SB;
        if (g < 13)       asm volatile("s_waitcnt vmcnt(24)" ::: "memory");
        else if (g == 13) asm volatile("s_waitcnt vmcnt(16)" ::: "memory");
        else if (g == 14) asm volatile("s_waitcnt vmcnt(8)"  ::: "memory");
        else              asm volatile("s_waitcnt vmcnt(0)"  ::: "memory");
        SB;
        bf16x8 xf[4];
#pragma unroll
        for (int vt = 0; vt < 4; ++vt)
            xf[vt] = *(const bf16x8*)(ringw + (((g & 3) * 4 + vt) << 10) + lane * 16);
#pragma unroll
        for (int vt = 0; vt < 4; ++vt)
#pragma unroll
            for (int nt = 0; nt < 4; ++nt)
                acc[vt][nt] = __builtin_amdgcn_mfma_f32_16x16x32_bf16(wfp[g & 3][nt], xf[vt], acc[vt][nt], 0, 0, 0);
        SB;
    }
#undef GATHER_ISSUE
#undef LOAD_W
#undef SB

    // Epilogue: cached stores (WRITE_SIZE exact at ~100 MB in r0/r4/r6).
#pragma unroll
    for (int vt = 0; vt < 4; ++vt) {
        const int n = nn[vt] + m16;
        const bool zero = (n == N_ - 1);
        float* orow = out + (size_t)(rowbase[vt] + m16) * O_ + quad * 4;
#pragma unroll
        for (int nt = 0; nt < 4; ++nt) {
            f32x4 bv = *(const f32x4*)(bias + nt * 16 + quad * 4);
            f32x4 v;
#pragma unroll
            for (int r = 0; r < 4; ++r) {
                float t = acc[vt][nt][r] + bv[r];
                t = t > 0.f ? t : (__expf(t) - 1.f); // ELU alpha=1
                v[r] = zero ? 0.f : t;
            }
            *(f32x4*)(orow + nt * 16) = v;
        }
    }
}

// ---- Main kernel: persistent blocks + per-batch dynamic work-stealing ----
// 512 blocks (2/CU), ALL co-resident -> no generation-quantization tail
// (r4: 1568 uniform blocks at 512 slots = 4 generations, last one 6% full =
// ~23 us of near-idle machine; occupancy counters 17.3%/9.3% in r4/r6 match
// 25%*(3.06/4) and 12.5%*(6.125/7)). Each block serves only batch blockIdx&7
// (XCD<->L2 affinity preserved, r5's lost-affinity mistake avoided); groups
// come from a per-batch atomic counter reset by prep (stream-ordered).
__global__ __launch_bounds__(256, 2) void spiral_kernel(
        const unsigned short* __restrict__ xb, const int* __restrict__ adj,
        const unsigned short* __restrict__ Wb, const float* __restrict__ bias,
        float* __restrict__ out, unsigned int* __restrict__ ctr) {
    __shared__ __align__(16) unsigned char ring[4][4][4][1024]; // 64 KB
    __shared__ unsigned int sh_g;

    const int tid  = threadIdx.x;
    const int lane = tid & 63;
    const int wv   = tid >> 6;
    const int m16  = lane & 15;
    const int quad = lane >> 4;
    const int b    = blockIdx.x & 7; // batch == intended XCD

    unsigned char* ringw = &ring[wv][0][0][0];

    for (;;) {
        __syncthreads(); // protects sh_g reuse; pipeline is already drained here
        if (tid == 0) sh_g = atomicAdd(&ctr[b], 1u);
        __syncthreads();
        const unsigned g = sh_g;
        if (g >= (unsigned)BPB) break;
        spiral_body(xb, adj, Wb, bias, out, ringw,
                    b, ((int)g * 4 + wv) * 4, lane, m16, quad);
    }
}

// ---- Fallback (ws too small): fp32-gather kernel ----
__global__ __launch_bounds__(256) void wconv_kernel(const float* __restrict__ W,
                                                    unsigned short* __restrict__ Wb) {
    int i = blockIdx.x * 256 + threadIdx.x;
    if (i < O_ * K_) {
        int j = i & 7, o = (i >> 3) & 63, qk = i >> 9;
        int quad = qk & 3, kt = qk >> 2;
        __hip_bfloat16 h = __float2bfloat16(W[o * K_ + kt * 32 + quad * 8 + j]);
        unsigned short u; memcpy(&u, &h, 2);
        Wb[i] = u;
    }
}

__global__ __launch_bounds__(256) void spiral_f32_kernel(
        const float* __restrict__ x, const int* __restrict__ adj,
        const unsigned short* __restrict__ Wb, const float* __restrict__ bias,
        float* __restrict__ out) {
    const int lane = threadIdx.x & 63;
    const int wv = threadIdx.x >> 6;
    const int m16 = lane & 15, quad = lane >> 4;
    const int b  = blockIdx.x & 7;
    const int jb = blockIdx.x >> 3;
    const int tib0 = (jb * 4 + wv) * 4;
    int rowbase[4], nn[4];
#pragma unroll
    for (int vt = 0; vt < 4; ++vt) {
        int t = tib0 + vt;
        if (t >= TPB) t = TPB - 1;
        nn[vt] = t * 16;
        rowbase[vt] = b * N_ + t * 16;
    }
    f32x4 acc[4][4];
#pragma unroll
    for (int vt = 0; vt < 4; ++vt)
#pragma unroll
        for (int nt = 0; nt < 4; ++nt) acc[vt][nt] = (f32x4){0.f,0.f,0.f,0.f};
    for (int kt = 0; kt < 16; ++kt) {
        bf16x8 wf[4];
#pragma unroll
        for (int nt = 0; nt < 4; ++nt)
            wf[nt] = *(const bf16x8*)(Wb + (size_t)((kt * 4 + quad) * 64 + nt * 16 + m16) * 8);
#pragma unroll
        for (int vt = 0; vt < 4; ++vt) {
            int a = adj[(size_t)(rowbase[vt] + m16) * S_ + kt];
            const float* xr = x + ((size_t)b * N_ + a) * F_ + quad * 8;
            f32x4 x0 = *(const f32x4*)xr;
            f32x4 x1 = *(const f32x4*)(xr + 4);
            bfpack af;
            af.h[0]=__float2bfloat16(x0[0]); af.h[1]=__float2bfloat16(x0[1]);
            af.h[2]=__float2bfloat16(x0[2]); af.h[3]=__float2bfloat16(x0[3]);
            af.h[4]=__float2bfloat16(x1[0]); af.h[5]=__float2bfloat16(x1[1]);
            af.h[6]=__float2bfloat16(x1[2]); af.h[7]=__float2bfloat16(x1[3]);
#pragma unroll
            for (int nt = 0; nt < 4; ++nt)
                acc[vt][nt] = __builtin_amdgcn_mfma_f32_16x16x32_bf16(wf[nt], af.v, acc[vt][nt], 0, 0, 0);
        }
    }
#pragma unroll
    for (int vt = 0; vt < 4; ++vt) {
        const int n = nn[vt] + m16;
        const bool zero = (n == N_ - 1);
        float* orow = out + (size_t)(rowbase[vt] + m16) * O_ + quad * 4;
#pragma unroll
        for (int nt = 0; nt < 4; ++nt) {
            f32x4 bv = *(const f32x4*)(bias + nt * 16 + quad * 4);
            f32x4 v;
#pragma unroll
            for (int r = 0; r < 4; ++r) {
                float t = acc[vt][nt][r] + bv[r];
                t = t > 0.f ? t : (__expf(t) - 1.f);
                v[r] = zero ? 0.f : t;
            }
            *(f32x4*)(orow + nt * 16) = v;
        }
    }
}

extern "C" void kernel_launch(void* const* d_in, const int* in_sizes, int n_in,
                              void* d_out, int out_size, void* d_ws, size_t ws_size,
                              hipStream_t stream) {
    const float* x    = (const float*)d_in[0];
    const int*   adj  = (const int*)d_in[1];
    const float* W    = (const float*)d_in[2];
    const float* bias = (const float*)d_in[3];
    float* out = (float*)d_out;

    const size_t wb_bytes = (size_t)O_ * K_ * 2;            // 64 KB
    const size_t xb_bytes = (size_t)XELEMS * 2;             // 25.6 MB
    const size_t ctr_off  = wb_bytes + xb_bytes;
    unsigned short* Wb = (unsigned short*)d_ws;
    unsigned short* xb = (unsigned short*)((char*)d_ws + wb_bytes);
    unsigned int*  ctr = (unsigned int*)((char*)d_ws + ctr_off);

    if (ws_size >= ctr_off + 32) {
        int grid_prep = 128 + (XELEMS / 8 + 255) / 256; // 128 + 6250
        hipLaunchKernelGGL(prep_kernel, dim3(grid_prep), dim3(256), 0, stream,
                           W, Wb, x, xb, ctr);
        hipLaunchKernelGGL(spiral_kernel, dim3(GRID_PERS), dim3(256), 0, stream,
                           xb, adj, Wb, bias, out, ctr);
    } else {
        hipLaunchKernelGGL(wconv_kernel, dim3(128), dim3(256), 0, stream, W, Wb);
        hipLaunchKernelGGL(spiral_f32_kernel, dim3(8 * BPB), dim3(256), 0, stream,
                           x, adj, Wb, bias, out);
    }
}

// Round 8
// 268.513 us; speedup vs baseline: 1.0240x; 1.0240x over previous
//
#include <hip/hip_runtime.h>
#include <hip/hip_bf16.h>
#include <string.h>

#define B_ 8
#define N_ 50000
#define F_ 32
#define S_ 16
#define O_ 64
#define K_ (F_ * S_)            // 512
#define XELEMS (B_ * N_ * F_)   // 12.8M
#define TPB (N_ / 16)           // 3125 tiles per batch
#define UPB 782                 // 4-tile work units per batch (782*4 = 3128 >= 3125)
#define BPB 196                 // blocks/batch for the static fallback path
#define GRID_PERS 512           // 2 blocks/CU, all co-resident

typedef __attribute__((ext_vector_type(8))) short bf16x8;
typedef __attribute__((ext_vector_type(4))) float f32x4;
typedef __attribute__((ext_vector_type(4))) int int4v;

union bfpack { bf16x8 v; __hip_bfloat16 h[8]; };

// ---- Prepass: W -> bf16 fragment-swizzled (64 KB) + x -> bf16 rows (25.6 MB) ----
// Also resets the 8 per-batch work counters (one 64 B line each; stream-ordered
// before spiral, runs every replay -> no host-side memset needed).
__global__ __launch_bounds__(256) void prep_kernel(const float* __restrict__ W,
                                                   unsigned short* __restrict__ Wb,
                                                   const float* __restrict__ x,
                                                   unsigned short* __restrict__ xb,
                                                   unsigned int* __restrict__ ctr) {
    int bid = blockIdx.x;
    if (bid == 0 && threadIdx.x < 8) ctr[threadIdx.x * 16] = 0u; // padded: 1 line/batch
    if (bid < 128) {
        int i = bid * 256 + threadIdx.x; // [0, 32768)
        int j = i & 7;
        int o = (i >> 3) & 63;
        int qk = i >> 9;
        int quad = qk & 3;
        int kt = qk >> 2;
        __hip_bfloat16 h = __float2bfloat16(W[o * K_ + kt * 32 + quad * 8 + j]);
        unsigned short u; memcpy(&u, &h, 2);
        Wb[i] = u;
    } else {
        int i = (bid - 128) * 256 + threadIdx.x; // [0, 1.6M) groups of 8
        if (i < XELEMS / 8) {
            size_t base = (size_t)i * 8;
            f32x4 a = __builtin_nontemporal_load((const f32x4*)(x + base));
            f32x4 b = __builtin_nontemporal_load((const f32x4*)(x + base + 4));
            bfpack p;
            p.h[0] = __float2bfloat16(a[0]); p.h[1] = __float2bfloat16(a[1]);
            p.h[2] = __float2bfloat16(a[2]); p.h[3] = __float2bfloat16(a[3]);
            p.h[4] = __float2bfloat16(b[0]); p.h[5] = __float2bfloat16(b[1]);
            p.h[6] = __float2bfloat16(b[2]); p.h[7] = __float2bfloat16(b[3]);
            *(bf16x8*)(xb + base) = p.v;
        }
    }
}

// ================= r4's 94 us spiral body, verbatim =================
// LDS-DMA deep pipeline: gathers via global_load_lds into a per-wave 4-slot
// ring (no dest VGPRs -> depth is structural), pinned issue order, counted
// vmcnt (24 steady / 16 / 8 / 0 tail), cached epilogue stores.
// Safe to call back-to-back per wave: entry with the previous unit's 16
// epilogue stores outstanding keeps the accounting exact (in-order retirement:
// first vmcnt(24) drains stores16+adj16+C0+W0, leaving C1..W3 = 24 in flight).
__device__ __forceinline__ void spiral_body(
        const unsigned short* __restrict__ xb, const int* __restrict__ adj,
        const unsigned short* __restrict__ Wb, const float* __restrict__ bias,
        float* __restrict__ out, unsigned char* ringw,
        int b, int tib0, int lane, int m16, int quad)
{
    int rowbase[4], nn[4];
#pragma unroll
    for (int vt = 0; vt < 4; ++vt) {
        int t = tib0 + vt;
        if (t >= TPB) t = TPB - 1; // clamp: duplicate identical stores, benign
        nn[vt] = t * 16;
        rowbase[vt] = b * N_ + t * 16;
    }
    const size_t xbase = (size_t)b * N_ * F_;

    // All adj up front (nt: read-once stream). 16 x int4.
    int4v aj_all[4][4]; // [vt][kt4]
#pragma unroll
    for (int vt = 0; vt < 4; ++vt)
#pragma unroll
        for (int kt4 = 0; kt4 < 4; ++kt4)
            aj_all[vt][kt4] = __builtin_nontemporal_load(
                (const int4v*)(adj + (size_t)(rowbase[vt] + m16) * S_ + kt4 * 4));

    f32x4 acc[4][4];
#pragma unroll
    for (int vt = 0; vt < 4; ++vt)
#pragma unroll
        for (int nt = 0; nt < 4; ++nt)
            acc[vt][nt] = (f32x4){0.f, 0.f, 0.f, 0.f};

    bf16x8 wfp[4][4]; // W fragment pipeline: [ring slot][nt], static indices only

#define GATHER_ISSUE(g_)                                                                   \
    do {                                                                                   \
        if ((g_) < 16) {                                                                   \
            const int kt4_ = (g_) >> 2, q_ = (g_) & 3;                                     \
            _Pragma("unroll")                                                              \
            for (int vt = 0; vt < 4; ++vt) {                                               \
                int a_ = aj_all[vt][kt4_][q_];                                             \
                const unsigned short* src_ = xb + xbase + (size_t)a_ * F_ + quad * 8;      \
                __builtin_amdgcn_global_load_lds(                                          \
                    (const __attribute__((address_space(1))) void*)src_,                   \
                    (__attribute__((address_space(3))) void*)(ringw + ((((g_) & 3) * 4 + vt) << 10)), \
                    16, 0, 0);                                                             \
            }                                                                              \
        }                                                                                  \
    } while (0)

#define LOAD_W(g_)                                                                         \
    do {                                                                                   \
        if ((g_) < 16) {                                                                   \
            _Pragma("unroll")                                                              \
            for (int nt = 0; nt < 4; ++nt)                                                 \
                wfp[(g_) & 3][nt] = *(const bf16x8*)(                                      \
                    Wb + (size_t)(((g_) * 4 + quad) * 64 + nt * 16 + m16) * 8);            \
        }                                                                                  \
    } while (0)

#define SB __builtin_amdgcn_sched_barrier(0)

    // Prologue FIFO: C0 W0 C1 W1 C2 W2.
    GATHER_ISSUE(0); SB; LOAD_W(0); SB;
    GATHER_ISSUE(1); SB; LOAD_W(1); SB;
    GATHER_ISSUE(2); SB; LOAD_W(2); SB;

#pragma unroll
    for (int g = 0; g < 16; ++g) {
        GATHER_ISSUE(g + 3); SB;
        LOAD_W(g + 3); SB;
        if (g < 13)       asm volatile("s_waitcnt vmcnt(24)" ::: "memory");
        else if (g == 13) asm volatile("s_waitcnt vmcnt(16)" ::: "memory");
        else if (g == 14) asm volatile("s_waitcnt vmcnt(8)"  ::: "memory");
        else              asm volatile("s_waitcnt vmcnt(0)"  ::: "memory");
        SB;
        bf16x8 xf[4];
#pragma unroll
        for (int vt = 0; vt < 4; ++vt)
            xf[vt] = *(const bf16x8*)(ringw + (((g & 3) * 4 + vt) << 10) + lane * 16);
#pragma unroll
        for (int vt = 0; vt < 4; ++vt)
#pragma unroll
            for (int nt = 0; nt < 4; ++nt)
                acc[vt][nt] = __builtin_amdgcn_mfma_f32_16x16x32_bf16(wfp[g & 3][nt], xf[vt], acc[vt][nt], 0, 0, 0);
        SB;
    }
#undef GATHER_ISSUE
#undef LOAD_W
#undef SB

    // Epilogue: cached stores (WRITE_SIZE exact at ~100 MB in r0/r4/r6).
#pragma unroll
    for (int vt = 0; vt < 4; ++vt) {
        const int n = nn[vt] + m16;
        const bool zero = (n == N_ - 1);
        float* orow = out + (size_t)(rowbase[vt] + m16) * O_ + quad * 4;
#pragma unroll
        for (int nt = 0; nt < 4; ++nt) {
            f32x4 bv = *(const f32x4*)(bias + nt * 16 + quad * 4);
            f32x4 v;
#pragma unroll
            for (int r = 0; r < 4; ++r) {
                float t = acc[vt][nt][r] + bv[r];
                t = t > 0.f ? t : (__expf(t) - 1.f); // ELU alpha=1
                v[r] = zero ? 0.f : t;
            }
            *(f32x4*)(orow + nt * 16) = v;
        }
    }
}

// ---- Main kernel: persistent blocks, per-WAVE dynamic work-stealing ----
// 512 blocks (2/CU) all co-resident. ZERO barriers: each wave independently
// grabs a 4-tile unit from its batch's padded atomic counter (lane 0 grabs,
// readfirstlane broadcasts). Waves never wait on each other, so one wave's
// prologue refill overlaps the other 7 waves' steady state on the CU — the
// overlap r7's block-wide __syncthreads destroyed. Batch = blockIdx&7 keeps
// the XCD<->L2 slice affinity; each counter line is touched by one XCD only.
__global__ __launch_bounds__(256, 2) void spiral_kernel(
        const unsigned short* __restrict__ xb, const int* __restrict__ adj,
        const unsigned short* __restrict__ Wb, const float* __restrict__ bias,
        float* __restrict__ out, unsigned int* __restrict__ ctr) {
    __shared__ __align__(16) unsigned char ring[4][4][4][1024]; // 64 KB

    const int tid  = threadIdx.x;
    const int lane = tid & 63;
    const int wv   = tid >> 6;
    const int m16  = lane & 15;
    const int quad = lane >> 4;
    const int b    = blockIdx.x & 7; // batch == intended XCD

    unsigned char* ringw = &ring[wv][0][0][0];
    unsigned int* ctrb = ctr + b * 16; // one 64 B line per batch

    for (;;) {
        unsigned u = 0;
        if (lane == 0) u = atomicAdd(ctrb, 1u);
        u = __builtin_amdgcn_readfirstlane(u);
        if (u >= (unsigned)UPB) break;
        spiral_body(xb, adj, Wb, bias, out, ringw,
                    b, (int)u * 4, lane, m16, quad);
    }
}

// ---- Fallback (ws too small): fp32-gather kernel ----
__global__ __launch_bounds__(256) void wconv_kernel(const float* __restrict__ W,
                                                    unsigned short* __restrict__ Wb) {
    int i = blockIdx.x * 256 + threadIdx.x;
    if (i < O_ * K_) {
        int j = i & 7, o = (i >> 3) & 63, qk = i >> 9;
        int quad = qk & 3, kt = qk >> 2;
        __hip_bfloat16 h = __float2bfloat16(W[o * K_ + kt * 32 + quad * 8 + j]);
        unsigned short u; memcpy(&u, &h, 2);
        Wb[i] = u;
    }
}

__global__ __launch_bounds__(256) void spiral_f32_kernel(
        const float* __restrict__ x, const int* __restrict__ adj,
        const unsigned short* __restrict__ Wb, const float* __restrict__ bias,
        float* __restrict__ out) {
    const int lane = threadIdx.x & 63;
    const int wv = threadIdx.x >> 6;
    const int m16 = lane & 15, quad = lane >> 4;
    const int b  = blockIdx.x & 7;
    const int jb = blockIdx.x >> 3;
    const int tib0 = (jb * 4 + wv) * 4;
    int rowbase[4], nn[4];
#pragma unroll
    for (int vt = 0; vt < 4; ++vt) {
        int t = tib0 + vt;
        if (t >= TPB) t = TPB - 1;
        nn[vt] = t * 16;
        rowbase[vt] = b * N_ + t * 16;
    }
    f32x4 acc[4][4];
#pragma unroll
    for (int vt = 0; vt < 4; ++vt)
#pragma unroll
        for (int nt = 0; nt < 4; ++nt) acc[vt][nt] = (f32x4){0.f,0.f,0.f,0.f};
    for (int kt = 0; kt < 16; ++kt) {
        bf16x8 wf[4];
#pragma unroll
        for (int nt = 0; nt < 4; ++nt)
            wf[nt] = *(const bf16x8*)(Wb + (size_t)((kt * 4 + quad) * 64 + nt * 16 + m16) * 8);
#pragma unroll
        for (int vt = 0; vt < 4; ++vt) {
            int a = adj[(size_t)(rowbase[vt] + m16) * S_ + kt];
            const float* xr = x + ((size_t)b * N_ + a) * F_ + quad * 8;
            f32x4 x0 = *(const f32x4*)xr;
            f32x4 x1 = *(const f32x4*)(xr + 4);
            bfpack af;
            af.h[0]=__float2bfloat16(x0[0]); af.h[1]=__float2bfloat16(x0[1]);
            af.h[2]=__float2bfloat16(x0[2]); af.h[3]=__float2bfloat16(x0[3]);
            af.h[4]=__float2bfloat16(x1[0]); af.h[5]=__float2bfloat16(x1[1]);
            af.h[6]=__float2bfloat16(x1[2]); af.h[7]=__float2bfloat16(x1[3]);
#pragma unroll
            for (int nt = 0; nt < 4; ++nt)
                acc[vt][nt] = __builtin_amdgcn_mfma_f32_16x16x32_bf16(wf[nt], af.v, acc[vt][nt], 0, 0, 0);
        }
    }
#pragma unroll
    for (int vt = 0; vt < 4; ++vt) {
        const int n = nn[vt] + m16;
        const bool zero = (n == N_ - 1);
        float* orow = out + (size_t)(rowbase[vt] + m16) * O_ + quad * 4;
#pragma unroll
        for (int nt = 0; nt < 4; ++nt) {
            f32x4 bv = *(const f32x4*)(bias + nt * 16 + quad * 4);
            f32x4 v;
#pragma unroll
            for (int r = 0; r < 4; ++r) {
                float t = acc[vt][nt][r] + bv[r];
                t = t > 0.f ? t : (__expf(t) - 1.f);
                v[r] = zero ? 0.f : t;
            }
            *(f32x4*)(orow + nt * 16) = v;
        }
    }
}

extern "C" void kernel_launch(void* const* d_in, const int* in_sizes, int n_in,
                              void* d_out, int out_size, void* d_ws, size_t ws_size,
                              hipStream_t stream) {
    const float* x    = (const float*)d_in[0];
    const int*   adj  = (const int*)d_in[1];
    const float* W    = (const float*)d_in[2];
    const float* bias = (const float*)d_in[3];
    float* out = (float*)d_out;

    const size_t wb_bytes = (size_t)O_ * K_ * 2;            // 64 KB
    const size_t xb_bytes = (size_t)XELEMS * 2;             // 25.6 MB
    const size_t ctr_off  = wb_bytes + xb_bytes;            // 128 B aligned
    unsigned short* Wb = (unsigned short*)d_ws;
    unsigned short* xb = (unsigned short*)((char*)d_ws + wb_bytes);
    unsigned int*  ctr = (unsigned int*)((char*)d_ws + ctr_off);

    if (ws_size >= ctr_off + 512) {
        int grid_prep = 128 + (XELEMS / 8 + 255) / 256; // 128 + 6250
        hipLaunchKernelGGL(prep_kernel, dim3(grid_prep), dim3(256), 0, stream,
                           W, Wb, x, xb, ctr);
        hipLaunchKernelGGL(spiral_kernel, dim3(GRID_PERS), dim3(256), 0, stream,
                           xb, adj, Wb, bias, out, ctr);
    } else {
        hipLaunchKernelGGL(wconv_kernel, dim3(128), dim3(256), 0, stream, W, Wb);
        hipLaunchKernelGGL(spiral_f32_kernel, dim3(8 * BPB), dim3(256), 0, stream,
                           x, adj, Wb, bias, out);
    }
}

// Round 9
// 229.297 us; speedup vs baseline: 1.1991x; 1.1710x over previous
//
#include <hip/hip_runtime.h>
#include <hip/hip_bf16.h>
#include <string.h>

#define B_ 8
#define N_ 50000
#define F_ 32
#define S_ 16
#define O_ 64
#define K_ (F_ * S_)            // 512
#define XELEMS (B_ * N_ * F_)   // 12.8M
#define TPB (N_ / 16)           // 3125 tiles per batch
#define BPB 196                 // blocks per batch (196*16 = 3136 >= 3125)

typedef __attribute__((ext_vector_type(8))) short bf16x8;
typedef __attribute__((ext_vector_type(4))) float f32x4;
typedef __attribute__((ext_vector_type(4))) int int4v;

union bfpack { bf16x8 v; __hip_bfloat16 h[8]; };

// ---- Prepass: W -> bf16 fragment-swizzled (64 KB) + x -> bf16 rows (25.6 MB) ----
// Wb[((kt*4 + quad)*64 + o)*8 + j] = bf16(W[o*512 + kt*32 + quad*8 + j])
__global__ __launch_bounds__(256) void prep_kernel(const float* __restrict__ W,
                                                   unsigned short* __restrict__ Wb,
                                                   const float* __restrict__ x,
                                                   unsigned short* __restrict__ xb) {
    int bid = blockIdx.x;
    if (bid < 128) {
        int i = bid * 256 + threadIdx.x; // [0, 32768)
        int j = i & 7;
        int o = (i >> 3) & 63;
        int qk = i >> 9;
        int quad = qk & 3;
        int kt = qk >> 2;
        __hip_bfloat16 h = __float2bfloat16(W[o * K_ + kt * 32 + quad * 8 + j]);
        unsigned short u; memcpy(&u, &h, 2);
        Wb[i] = u;
    } else {
        int i = (bid - 128) * 256 + threadIdx.x; // [0, 1.6M) groups of 8
        if (i < XELEMS / 8) {
            size_t base = (size_t)i * 8;
            f32x4 a = __builtin_nontemporal_load((const f32x4*)(x + base));
            f32x4 b = __builtin_nontemporal_load((const f32x4*)(x + base + 4));
            bfpack p;
            p.h[0] = __float2bfloat16(a[0]); p.h[1] = __float2bfloat16(a[1]);
            p.h[2] = __float2bfloat16(a[2]); p.h[3] = __float2bfloat16(a[3]);
            p.h[4] = __float2bfloat16(b[0]); p.h[5] = __float2bfloat16(b[1]);
            p.h[6] = __float2bfloat16(b[2]); p.h[7] = __float2bfloat16(b[3]);
            *(bf16x8*)(xb + base) = p.v;
        }
    }
}

// ---- Main kernel: LDS-DMA deep-pipelined gathered GEMM (r4 structure) ----
// Static 1568-block grid, batch = blockIdx&7 (XCD<->L2 affinity). Gathers via
// __builtin_amdgcn_global_load_lds into a per-wave 4-slot ring (no dest VGPRs
// -> pipeline depth is structural), pinned issue order (sched_barrier), counted
// s_waitcnt vmcnt(24) steady / 16 / 8 / 0 tail. Cached epilogue stores.
// This is the measured optimum: the kernel sits at the per-CU miss-path wall
// (~6.4M random 64B line-misses, ~MSHR/latency ~= 0.14 lines/cy/CU ~= 72 us
// floor + overheads = ~94 us). Depth/waves/residency/scheduling levers all
// measured neutral-or-negative (r2,r3,r6,r7,r8).
__global__ __launch_bounds__(256, 2) void spiral_kernel(
        const unsigned short* __restrict__ xb, const int* __restrict__ adj,
        const unsigned short* __restrict__ Wb, const float* __restrict__ bias,
        float* __restrict__ out) {
    const int lane = threadIdx.x & 63;
    const int wv   = threadIdx.x >> 6;
    const int m16  = lane & 15;
    const int quad = lane >> 4;

    const int b  = blockIdx.x & 7;   // batch == intended XCD
    const int jb = blockIdx.x >> 3;  // 0..195 block-within-batch
    const int tib0 = (jb * 4 + wv) * 4;

    // [wave][ring slot][vt][1 KB]: lane deposits its 16 B at +lane*16. 64 KB.
    __shared__ __align__(16) unsigned char ring[4][4][4][1024];

    int rowbase[4]; // b*N + n0 (n0 = tile start vertex within batch)
    int nn[4];
#pragma unroll
    for (int vt = 0; vt < 4; ++vt) {
        int t = tib0 + vt;
        if (t >= TPB) t = TPB - 1; // clamp within batch: duplicate identical stores, benign
        nn[vt] = t * 16;
        rowbase[vt] = b * N_ + t * 16;
    }
    const size_t xbase = (size_t)b * N_ * F_;

    // All adj up front (nt: read-once stream). 16 x int4 = 64 VGPRs.
    int4v aj_all[4][4]; // [vt][kt4]
#pragma unroll
    for (int vt = 0; vt < 4; ++vt)
#pragma unroll
        for (int kt4 = 0; kt4 < 4; ++kt4)
            aj_all[vt][kt4] = __builtin_nontemporal_load(
                (const int4v*)(adj + (size_t)(rowbase[vt] + m16) * S_ + kt4 * 4));

    f32x4 acc[4][4];
#pragma unroll
    for (int vt = 0; vt < 4; ++vt)
#pragma unroll
        for (int nt = 0; nt < 4; ++nt)
            acc[vt][nt] = (f32x4){0.f, 0.f, 0.f, 0.f};

    bf16x8 wfp[4][4]; // W fragment pipeline: [ring slot][nt], all indices static

    // Issue gathers for kt = g_ into ring slot g_&3 (4 LDS-DMA, one per vt).
#define GATHER_ISSUE(g_)                                                                   \
    do {                                                                                   \
        if ((g_) < 16) {                                                                   \
            const int kt4_ = (g_) >> 2, q_ = (g_) & 3;                                     \
            _Pragma("unroll")                                                              \
            for (int vt = 0; vt < 4; ++vt) {                                               \
                int a_ = aj_all[vt][kt4_][q_];                                             \
                const unsigned short* src_ = xb + xbase + (size_t)a_ * F_ + quad * 8;      \
                __builtin_amdgcn_global_load_lds(                                          \
                    (const __attribute__((address_space(1))) void*)src_,                   \
                    (__attribute__((address_space(3))) void*)&ring[wv][(g_) & 3][vt][0],   \
                    16, 0, 0);                                                             \
            }                                                                              \
        }                                                                                  \
    } while (0)

#define LOAD_W(g_)                                                                         \
    do {                                                                                   \
        if ((g_) < 16) {                                                                   \
            _Pragma("unroll")                                                              \
            for (int nt = 0; nt < 4; ++nt)                                                 \
                wfp[(g_) & 3][nt] = *(const bf16x8*)(                                      \
                    Wb + (size_t)(((g_) * 4 + quad) * 64 + nt * 16 + m16) * 8);            \
        }                                                                                  \
    } while (0)

#define SB __builtin_amdgcn_sched_barrier(0)

    // Prologue: FIFO = C0 W0 C1 W1 C2 W2 (24 vmem in flight; earlier adj
    // loads drain under the same counted waits — in-order retirement).
    GATHER_ISSUE(0); SB; LOAD_W(0); SB;
    GATHER_ISSUE(1); SB; LOAD_W(1); SB;
    GATHER_ISSUE(2); SB; LOAD_W(2); SB;

#pragma unroll
    for (int g = 0; g < 16; ++g) {
        // Issue region: C_{g+3} then W_{g+3} (keeps FIFO pattern ...C W C W...).
        GATHER_ISSUE(g + 3); SB;
        LOAD_W(g + 3); SB;
        // Counted wait: drain C_g + W_g, keep the 3 newer C/W groups in flight.
        if (g < 13)       asm volatile("s_waitcnt vmcnt(24)" ::: "memory");
        else if (g == 13) asm volatile("s_waitcnt vmcnt(16)" ::: "memory");
        else if (g == 14) asm volatile("s_waitcnt vmcnt(8)"  ::: "memory");
        else              asm volatile("s_waitcnt vmcnt(0)"  ::: "memory");
        SB;
        // Consume slot g&3: each lane reads back its own 16 B per vt.
        bf16x8 xf[4];
#pragma unroll
        for (int vt = 0; vt < 4; ++vt)
            xf[vt] = *(const bf16x8*)&ring[wv][g & 3][vt][(size_t)lane * 16];
#pragma unroll
        for (int vt = 0; vt < 4; ++vt)
#pragma unroll
            for (int nt = 0; nt < 4; ++nt)
                // A = W-tile (m = o_local), B = x-tile (n = vertex)
                acc[vt][nt] = __builtin_amdgcn_mfma_f32_16x16x32_bf16(wfp[g & 3][nt], xf[vt], acc[vt][nt], 0, 0, 0);
        SB;
    }
#undef GATHER_ISSUE
#undef LOAD_W
#undef SB

    // Epilogue (cached stores, WRITE_SIZE exact at ~100 MB).
    // D layout: col = lane&15 = vertex, row = quad*4 + r = o within nt-tile.
#pragma unroll
    for (int vt = 0; vt < 4; ++vt) {
        const int n = nn[vt] + m16;
        const bool zero = (n == N_ - 1);
        float* orow = out + (size_t)(rowbase[vt] + m16) * O_ + quad * 4;
#pragma unroll
        for (int nt = 0; nt < 4; ++nt) {
            f32x4 bv = *(const f32x4*)(bias + nt * 16 + quad * 4);
            f32x4 v;
#pragma unroll
            for (int r = 0; r < 4; ++r) {
                float t = acc[vt][nt][r] + bv[r];
                t = t > 0.f ? t : (__expf(t) - 1.f); // ELU alpha=1
                v[r] = zero ? 0.f : t;
            }
            *(f32x4*)(orow + nt * 16) = v;
        }
    }
}

// ---- Fallback (ws too small): fp32-gather kernel ----
__global__ __launch_bounds__(256) void wconv_kernel(const float* __restrict__ W,
                                                    unsigned short* __restrict__ Wb) {
    int i = blockIdx.x * 256 + threadIdx.x;
    if (i < O_ * K_) {
        int j = i & 7, o = (i >> 3) & 63, qk = i >> 9;
        int quad = qk & 3, kt = qk >> 2;
        __hip_bfloat16 h = __float2bfloat16(W[o * K_ + kt * 32 + quad * 8 + j]);
        unsigned short u; memcpy(&u, &h, 2);
        Wb[i] = u;
    }
}

__global__ __launch_bounds__(256) void spiral_f32_kernel(
        const float* __restrict__ x, const int* __restrict__ adj,
        const unsigned short* __restrict__ Wb, const float* __restrict__ bias,
        float* __restrict__ out) {
    const int lane = threadIdx.x & 63;
    const int wv = threadIdx.x >> 6;
    const int m16 = lane & 15, quad = lane >> 4;
    const int b  = blockIdx.x & 7;
    const int jb = blockIdx.x >> 3;
    const int tib0 = (jb * 4 + wv) * 4;
    int rowbase[4], nn[4];
#pragma unroll
    for (int vt = 0; vt < 4; ++vt) {
        int t = tib0 + vt;
        if (t >= TPB) t = TPB - 1;
        nn[vt] = t * 16;
        rowbase[vt] = b * N_ + t * 16;
    }
    f32x4 acc[4][4];
#pragma unroll
    for (int vt = 0; vt < 4; ++vt)
#pragma unroll
        for (int nt = 0; nt < 4; ++nt) acc[vt][nt] = (f32x4){0.f,0.f,0.f,0.f};
    for (int kt = 0; kt < 16; ++kt) {
        bf16x8 wf[4];
#pragma unroll
        for (int nt = 0; nt < 4; ++nt)
            wf[nt] = *(const bf16x8*)(Wb + (size_t)((kt * 4 + quad) * 64 + nt * 16 + m16) * 8);
#pragma unroll
        for (int vt = 0; vt < 4; ++vt) {
            int a = adj[(size_t)(rowbase[vt] + m16) * S_ + kt];
            const float* xr = x + ((size_t)b * N_ + a) * F_ + quad * 8;
            f32x4 x0 = *(const f32x4*)xr;
            f32x4 x1 = *(const f32x4*)(xr + 4);
            bfpack af;
            af.h[0]=__float2bfloat16(x0[0]); af.h[1]=__float2bfloat16(x0[1]);
            af.h[2]=__float2bfloat16(x0[2]); af.h[3]=__float2bfloat16(x0[3]);
            af.h[4]=__float2bfloat16(x1[0]); af.h[5]=__float2bfloat16(x1[1]);
            af.h[6]=__float2bfloat16(x1[2]); af.h[7]=__float2bfloat16(x1[3]);
#pragma unroll
            for (int nt = 0; nt < 4; ++nt)
                acc[vt][nt] = __builtin_amdgcn_mfma_f32_16x16x32_bf16(wf[nt], af.v, acc[vt][nt], 0, 0, 0);
        }
    }
#pragma unroll
    for (int vt = 0; vt < 4; ++vt) {
        const int n = nn[vt] + m16;
        const bool zero = (n == N_ - 1);
        float* orow = out + (size_t)(rowbase[vt] + m16) * O_ + quad * 4;
#pragma unroll
        for (int nt = 0; nt < 4; ++nt) {
            f32x4 bv = *(const f32x4*)(bias + nt * 16 + quad * 4);
            f32x4 v;
#pragma unroll
            for (int r = 0; r < 4; ++r) {
                float t = acc[vt][nt][r] + bv[r];
                t = t > 0.f ? t : (__expf(t) - 1.f);
                v[r] = zero ? 0.f : t;
            }
            *(f32x4*)(orow + nt * 16) = v;
        }
    }
}

extern "C" void kernel_launch(void* const* d_in, const int* in_sizes, int n_in,
                              void* d_out, int out_size, void* d_ws, size_t ws_size,
                              hipStream_t stream) {
    const float* x    = (const float*)d_in[0];
    const int*   adj  = (const int*)d_in[1];
    const float* W    = (const float*)d_in[2];
    const float* bias = (const float*)d_in[3];
    float* out = (float*)d_out;

    const size_t wb_bytes = (size_t)O_ * K_ * 2;            // 64 KB
    const size_t xb_bytes = (size_t)XELEMS * 2;             // 25.6 MB
    unsigned short* Wb = (unsigned short*)d_ws;
    unsigned short* xb = (unsigned short*)((char*)d_ws + wb_bytes);

    const int grid_main = 8 * BPB; // 1568 blocks, batch = blockIdx % 8

    if (ws_size >= wb_bytes + xb_bytes) {
        int grid_prep = 128 + (XELEMS / 8 + 255) / 256; // 128 + 6250
        hipLaunchKernelGGL(prep_kernel, dim3(grid_prep), dim3(256), 0, stream, W, Wb, x, xb);
        hipLaunchKernelGGL(spiral_kernel, dim3(grid_main), dim3(256), 0, stream,
                           xb, adj, Wb, bias, out);
    } else {
        hipLaunchKernelGGL(wconv_kernel, dim3(128), dim3(256), 0, stream, W, Wb);
        hipLaunchKernelGGL(spiral_f32_kernel, dim3(grid_main), dim3(256), 0, stream,
                           x, adj, Wb, bias, out);
    }
}